// Round 2
// baseline (622.858 us; speedup 1.0000x reference)
//
#include <hip/hip_runtime.h>
#include <hip/hip_bf16.h>
#include <float.h>

#define BB 64
#define NN 900
#define CC 91
#define MM 128
#define BIG 1e18

// ---------------------------------------------------------------------------
// Kernel 1: cost matrix, stored TRANSPOSED as costT[b][t (M)][p (N)] f32,
// matching _lsa's internal layout after cost.T (n=M rows, m=N cols).
// Mirrors reference f32 math: two-pass softmax (max, sum(exp), e/sum),
// L1 in cxcywh space, GIoU in xyxy space, weights (1,5,2).
// ---------------------------------------------------------------------------
__global__ __launch_bounds__(256) void cost_kernel(
    const float* __restrict__ logits,   // [B,N,C]
    const float* __restrict__ boxes,    // [B,N,4]
    const int*   __restrict__ tlabels,  // [B,M]
    const float* __restrict__ tboxes,   // [B,M,4]
    float* __restrict__ costT)          // [B,M,N]
{
    const int b  = blockIdx.y;
    const int pi = blockIdx.x * blockDim.x + threadIdx.x;

    __shared__ float s_tb[MM][4];
    __shared__ int   s_tl[MM];
    if (threadIdx.x < MM) {
        s_tl[threadIdx.x] = tlabels[b * MM + threadIdx.x];
        #pragma unroll
        for (int k = 0; k < 4; ++k)
            s_tb[threadIdx.x][k] = tboxes[((size_t)b * MM + threadIdx.x) * 4 + k];
    }
    __syncthreads();
    if (pi >= NN) return;

    const float* lg = logits + ((size_t)b * NN + pi) * CC;
    float mx = -INFINITY;
    for (int c = 0; c < CC; ++c) mx = fmaxf(mx, lg[c]);
    float ssum = 0.f;
    for (int c = 0; c < CC; ++c) ssum += expf(lg[c] - mx);

    const float* bx = boxes + ((size_t)b * NN + pi) * 4;
    const float cx = bx[0], cy = bx[1], w = bx[2], h = bx[3];
    const float px0 = cx - 0.5f * w, py0 = cy - 0.5f * h;
    const float px1 = cx + 0.5f * w, py1 = cy + 0.5f * h;
    const float parea = (px1 - px0) * (py1 - py0);

    float* out = costT + (size_t)b * MM * NN + pi;
    for (int j = 0; j < MM; ++j) {
        const float tcx = s_tb[j][0], tcy = s_tb[j][1], tw = s_tb[j][2], th = s_tb[j][3];
        // L1 (cxcywh)
        float l1 = ((fabsf(cx - tcx) + fabsf(cy - tcy)) + fabsf(w - tw)) + fabsf(h - th);
        // GIoU (xyxy)
        const float tx0 = tcx - 0.5f * tw, ty0 = tcy - 0.5f * th;
        const float tx1 = tcx + 0.5f * tw, ty1 = tcy + 0.5f * th;
        float iw = fminf(px1, tx1) - fmaxf(px0, tx0); iw = fmaxf(iw, 0.f);
        float ih = fminf(py1, ty1) - fmaxf(py0, ty0); ih = fmaxf(ih, 0.f);
        const float inter = iw * ih;
        const float tarea = (tx1 - tx0) * (ty1 - ty0);
        const float uni   = parea + tarea - inter;
        const float iou   = inter / (uni + 1e-6f);
        const float enc   = (fmaxf(px1, tx1) - fminf(px0, tx0)) *
                            (fmaxf(py1, ty1) - fminf(py0, ty0)) + 1e-6f;
        const float giou  = iou - (enc - uni) / enc;
        // class cost
        const float pcls = expf(lg[s_tl[j]] - mx) / ssum;
        const float cost = (1.0f * (-pcls) + 5.0f * l1) + 2.0f * (-giou);
        out[(size_t)j * NN] = cost;
    }
}

// ---------------------------------------------------------------------------
// Kernel 2: Jonker-Volgenant LSA, one block per batch, f64 duals in LDS.
// Replicates the reference's transposed path (n=M=128 rows, m=N=900 cols),
// including np.argmin first-index tie-break.
// ---------------------------------------------------------------------------
__global__ __launch_bounds__(256) void lsa_kernel(
    const float* __restrict__ costT,  // [B,M,N]
    int* __restrict__ out)            // rows [B,M] then cols [B,M], int32
{
    const int b    = blockIdx.x;
    const int tid  = threadIdx.x;
    const int lane = tid & 63;
    const int wid  = tid >> 6;

    __shared__ double s_v[NN + 1];
    __shared__ double s_minv[NN + 1];
    __shared__ double s_u[MM + 1];
    __shared__ int    s_p[NN + 1];
    __shared__ int    s_way[NN + 1];
    __shared__ unsigned char s_used[NN + 1];
    __shared__ int    s_c4r[MM];
    __shared__ double s_rv[4];
    __shared__ int    s_ri[4];

    for (int j = tid; j <= NN; j += 256) { s_v[j] = 0.0; s_p[j] = 0; s_way[j] = 0; }
    for (int i = tid; i <= MM; i += 256) s_u[i] = 0.0;
    __syncthreads();

    const float* cb = costT + (size_t)b * MM * NN;

    for (int i = 1; i <= MM; ++i) {
        for (int j = tid; j <= NN; j += 256) { s_minv[j] = BIG; s_used[j] = 0; }
        if (tid == 0) s_p[0] = i;
        __syncthreads();

        int j0 = 0;
        int j1 = 0;
        while (true) {
            const int i0 = s_p[j0];
            const double ui0 = s_u[i0];
            const float* crow = cb + (size_t)(i0 - 1) * NN;

            double bv = BIG;
            int    bj = 0x7fffffff;
            for (int j = 1 + tid; j <= NN; j += 256) {
                if (!s_used[j] && j != j0) {
                    const double cur = (double)crow[j - 1] - ui0 - s_v[j];
                    if (cur < s_minv[j]) { s_minv[j] = cur; s_way[j] = j0; }
                    const double mv = s_minv[j];
                    if (mv < bv) { bv = mv; bj = j; }  // strict <: keeps smallest j
                }
            }
            // wave-level (value, index) argmin, first-index tie-break
            #pragma unroll
            for (int off = 32; off; off >>= 1) {
                const double ov = __shfl_down(bv, off);
                const int    oj = __shfl_down(bj, off);
                if (ov < bv || (ov == bv && oj < bj)) { bv = ov; bj = oj; }
            }
            if (lane == 0) { s_rv[wid] = bv; s_ri[wid] = bj; }
            __syncthreads();   // scan + leader writes complete

            double delta = s_rv[0];
            j1 = s_ri[0];
            #pragma unroll
            for (int w = 1; w < 4; ++w) {
                const double ov = s_rv[w]; const int oj = s_ri[w];
                if (ov < delta || (ov == delta && oj < j1)) { delta = ov; j1 = oj; }
            }

            // dual updates (j0 becomes used this iteration, matching reference)
            for (int j = tid; j <= NN; j += 256) {
                if (j == j0) {
                    s_used[j] = 1;
                    s_u[s_p[j]] += delta;
                    s_v[j] -= delta;
                } else if (s_used[j]) {
                    s_u[s_p[j]] += delta;
                    s_v[j] -= delta;
                } else {
                    s_minv[j] -= delta;
                }
            }
            __syncthreads();   // updates complete

            if (s_p[j1] == 0) break;
            j0 = j1;
        }

        if (tid == 0) {  // augment along 'way' chain
            int ja = j1;
            while (ja) {
                const int jb = s_way[ja];
                s_p[ja] = s_p[jb];
                ja = jb;
            }
        }
        __syncthreads();
    }

    // col4row: target t -> matched pred index
    for (int j = 1 + tid; j <= NN; j += 256) {
        const int pj = s_p[j];
        if (pj > 0) s_c4r[pj - 1] = j - 1;
    }
    __syncthreads();

    // transposed return: order = argsort(col4row) (distinct values);
    // rows = sorted pred indices, cols = the target permutation.
    if (tid < MM) {
        const int val = s_c4r[tid];
        int rank = 0;
        for (int t = 0; t < MM; ++t) rank += (s_c4r[t] < val);
        out[(size_t)b * MM + rank] = val;                      // rows
        out[(size_t)BB * MM + (size_t)b * MM + rank] = tid;    // cols
    }
}

extern "C" void kernel_launch(void* const* d_in, const int* in_sizes, int n_in,
                              void* d_out, int out_size, void* d_ws, size_t ws_size,
                              hipStream_t stream) {
    const float* logits  = (const float*)d_in[0];   // [64,900,91] f32
    const float* boxes   = (const float*)d_in[1];   // [64,900,4]  f32
    const int*   tlabels = (const int*)d_in[2];     // [64,128]    i32 (from i64)
    const float* tboxes  = (const float*)d_in[3];   // [64,128,4]  f32
    int*   out   = (int*)d_out;                     // rows[64,128] ++ cols[64,128], int32
    float* costT = (float*)d_ws;                    // [64,128,900] f32 = 28.1 MB

    dim3 g1((NN + 255) / 256, BB);
    cost_kernel<<<g1, 256, 0, stream>>>(logits, boxes, tlabels, tboxes, costT);
    lsa_kernel<<<BB, 256, 0, stream>>>(costT, out);
}

// Round 3
// 551.143 us; speedup vs baseline: 1.1301x; 1.1301x over previous
//
#include <hip/hip_runtime.h>
#include <hip/hip_bf16.h>
#include <float.h>

#define BB 64
#define NN 900
#define CC 91
#define MM 128
#define BIG 1e18
#define NSLOT 15              // 15*64 = 960 >= 900 columns per lane-slot grid
#define LAST_VALID 4          // slot 14 valid for lanes 0..3 (896+lane < 900)
#define TPB_C 128

// ---------------------------------------------------------------------------
// Kernel 1: cost matrix, stored TRANSPOSED as costT[b][t (M)][p (N)] f32.
// 128 preds per block; logits staged in LDS via coalesced float4 loads.
// Math identical to the round-2 passing kernel (two-pass softmax, L1, GIoU).
// ---------------------------------------------------------------------------
__global__ __launch_bounds__(TPB_C) void cost_kernel(
    const float* __restrict__ logits,   // [B,N,C]
    const float* __restrict__ boxes,    // [B,N,4]
    const int*   __restrict__ tlabels,  // [B,M]
    const float* __restrict__ tboxes,   // [B,M,4]
    float* __restrict__ costT)          // [B,M,N]
{
    const int b   = blockIdx.y;
    const int p0  = blockIdx.x * TPB_C;
    const int cnt = min(TPB_C, NN - p0);
    const int tid = threadIdx.x;

    __shared__ float s_lg[TPB_C * CC];   // 46592 B
    __shared__ float s_tb[MM][4];
    __shared__ int   s_tl[MM];

    // stage targets (TPB_C == MM == 128)
    {
        s_tl[tid] = tlabels[b * MM + tid];
        const float4 tb4 = ((const float4*)tboxes)[(size_t)b * MM + tid];
        s_tb[tid][0] = tb4.x; s_tb[tid][1] = tb4.y;
        s_tb[tid][2] = tb4.z; s_tb[tid][3] = tb4.w;
    }
    // stage logits, coalesced float4 (base is 16B-aligned: (b*900+p0)*91*4 % 16 == 0)
    {
        const float* gbase = logits + ((size_t)b * NN + p0) * CC;
        const int total = cnt * CC;
        const int n4 = total >> 2;
        for (int k = tid; k < n4; k += TPB_C)
            ((float4*)s_lg)[k] = ((const float4*)gbase)[k];
        for (int k = (n4 << 2) + tid; k < total; k += TPB_C)
            s_lg[k] = gbase[k];
    }
    __syncthreads();
    if (tid >= cnt) return;

    const float* lg = s_lg + tid * CC;
    float mx = -INFINITY;
    for (int c = 0; c < CC; ++c) mx = fmaxf(mx, lg[c]);
    float ssum = 0.f;
    for (int c = 0; c < CC; ++c) ssum += expf(lg[c] - mx);

    const float4 bx4 = ((const float4*)boxes)[(size_t)b * NN + p0 + tid];
    const float cx = bx4.x, cy = bx4.y, w = bx4.z, h = bx4.w;
    const float px0 = cx - 0.5f * w, py0 = cy - 0.5f * h;
    const float px1 = cx + 0.5f * w, py1 = cy + 0.5f * h;
    const float parea = (px1 - px0) * (py1 - py0);

    float* outp = costT + (size_t)b * MM * NN + p0 + tid;
    for (int j = 0; j < MM; ++j) {
        const float tcx = s_tb[j][0], tcy = s_tb[j][1], tw = s_tb[j][2], th = s_tb[j][3];
        float l1 = ((fabsf(cx - tcx) + fabsf(cy - tcy)) + fabsf(w - tw)) + fabsf(h - th);
        const float tx0 = tcx - 0.5f * tw, ty0 = tcy - 0.5f * th;
        const float tx1 = tcx + 0.5f * tw, ty1 = tcy + 0.5f * th;
        float iw = fminf(px1, tx1) - fmaxf(px0, tx0); iw = fmaxf(iw, 0.f);
        float ih = fminf(py1, ty1) - fmaxf(py0, ty0); ih = fmaxf(ih, 0.f);
        const float inter = iw * ih;
        const float tarea = (tx1 - tx0) * (ty1 - ty0);
        const float uni   = parea + tarea - inter;
        const float iou   = inter / (uni + 1e-6f);
        const float enc   = (fmaxf(px1, tx1) - fminf(px0, tx0)) *
                            (fmaxf(py1, ty1) - fminf(py0, ty0)) + 1e-6f;
        const float giou  = iou - (enc - uni) / enc;
        const float pcls  = expf(lg[s_tl[j]] - mx) / ssum;
        const float cost  = (1.0f * (-pcls) + 5.0f * l1) + 2.0f * (-giou);
        outp[(size_t)j * NN] = cost;
    }
}

// ---------------------------------------------------------------------------
// Kernel 2: Jonker-Volgenant LSA. ONE WAVE (64 lanes) per batch.
// Lane-register-resident minv/v (15 slots each, statically unrolled);
// u/p/way in LDS. Wave-synchronous: no __syncthreads in the hot loop.
// Semantics identical to the round-2 passing kernel (incl. np.argmin
// first-index tie-break via (value, j) butterfly reduce).
// ---------------------------------------------------------------------------
__global__ __launch_bounds__(64) void lsa_kernel(
    const float* __restrict__ costT,  // [B,M,N]
    int* __restrict__ out)            // rows [B,M] then cols [B,M], int32
{
    const int b    = blockIdx.x;
    const int lane = threadIdx.x;

    __shared__ double s_u[MM + 1];
    __shared__ int    s_p[NN + 1];
    __shared__ int    s_way[NN + 1];
    __shared__ int    s_c4r[MM];

    double v[NSLOT], minv[NSLOT];
    int    preg[NSLOT];

    for (int j = lane; j <= NN; j += 64) s_p[j] = 0;
    for (int i = lane; i <= MM; i += 64) s_u[i] = 0.0;
    #pragma unroll
    for (int s = 0; s < NSLOT; ++s) { v[s] = 0.0; preg[s] = 0; }
    __syncthreads();

    const float* cb = costT + (size_t)b * MM * NN;

    for (int i = 1; i <= MM; ++i) {
        unsigned used_mask = 0;
        #pragma unroll
        for (int s = 0; s < NSLOT; ++s) minv[s] = BIG;
        if (lane == 0) s_p[0] = i;
        int j0 = 0, i0 = i;

        while (true) {
            // mark j0 used (column 0 is virtual, handled by lane 0's u[i] update)
            if (j0 > 0) {
                const int jp = j0 - 1;
                if ((jp & 63) == lane) used_mask |= 1u << (jp >> 6);
            }
            const double ui0 = s_u[i0];          // uniform address -> broadcast
            const float* crow = cb + (size_t)(i0 - 1) * NN;

            // load this lane's cost entries (coalesced per slot)
            float cv[NSLOT];
            #pragma unroll
            for (int s = 0; s < NSLOT; ++s) {
                const bool valid = (s < NSLOT - 1) || (lane < LAST_VALID);
                cv[s] = valid ? crow[s * 64 + lane] : 0.f;
            }

            // scan + per-lane argmin (ascending j within lane, strict <)
            double bv = BIG; int bj = 0x7fffffff;
            #pragma unroll
            for (int s = 0; s < NSLOT; ++s) {
                const bool valid = (s < NSLOT - 1) || (lane < LAST_VALID);
                if (valid && !((used_mask >> s) & 1u)) {
                    const int j = s * 64 + lane + 1;
                    const double cur = (double)cv[s] - ui0 - v[s];
                    if (cur < minv[s]) { minv[s] = cur; s_way[j] = j0; }
                    if (minv[s] < bv) { bv = minv[s]; bj = j; }
                }
            }
            // 64-lane butterfly argmin, first-index (smallest j) tie-break
            #pragma unroll
            for (int m = 1; m < 64; m <<= 1) {
                const double ov = __shfl_xor(bv, m);
                const int    oj = __shfl_xor(bj, m);
                if (ov < bv || (ov == bv && oj < bj)) { bv = ov; bj = oj; }
            }
            const double delta = bv;
            const int    j1    = bj;

            // dual updates. u[p[used]] are distinct rows (matching) -> no alias;
            // split into gather-reads then writes to avoid serialized RMW chains.
            if (lane == 0) s_u[i] += delta;      // u[p[0]] = u[i], every iteration
            double uval[NSLOT];
            #pragma unroll
            for (int s = 0; s < NSLOT; ++s) {
                const bool valid = (s < NSLOT - 1) || (lane < LAST_VALID);
                if (valid && ((used_mask >> s) & 1u)) uval[s] = s_u[preg[s]];
            }
            #pragma unroll
            for (int s = 0; s < NSLOT; ++s) {
                const bool valid = (s < NSLOT - 1) || (lane < LAST_VALID);
                if (valid) {
                    if ((used_mask >> s) & 1u) {
                        s_u[preg[s]] = uval[s] + delta;
                        v[s] -= delta;
                    } else {
                        minv[s] -= delta;
                    }
                }
            }

            const int pj1 = s_p[j1];             // uniform address -> broadcast
            if (pj1 == 0) {
                if (lane == 0) {                 // augment along 'way' chain
                    int ja = j1;
                    while (ja) {
                        const int jb = s_way[ja];
                        s_p[ja] = s_p[jb];
                        ja = jb;
                    }
                }
                break;
            }
            j0 = j1; i0 = pj1;
        }

        // refresh cached p[j] for this lane's columns (p changed on the path)
        #pragma unroll
        for (int s = 0; s < NSLOT; ++s) {
            const bool valid = (s < NSLOT - 1) || (lane < LAST_VALID);
            if (valid) preg[s] = s_p[s * 64 + lane + 1];
        }
    }

    // col4row: target t -> matched pred index
    for (int j = 1 + lane; j <= NN; j += 64) {
        const int pj = s_p[j];
        if (pj > 0) s_c4r[pj - 1] = j - 1;
    }
    __syncthreads();

    // transposed return: rows = sorted pred indices, cols = target permutation
    for (int t = lane; t < MM; t += 64) {
        const int val = s_c4r[t];
        int rank = 0;
        for (int q = 0; q < MM; ++q) rank += (s_c4r[q] < val);
        out[(size_t)b * MM + rank] = val;
        out[(size_t)BB * MM + (size_t)b * MM + rank] = t;
    }
}

extern "C" void kernel_launch(void* const* d_in, const int* in_sizes, int n_in,
                              void* d_out, int out_size, void* d_ws, size_t ws_size,
                              hipStream_t stream) {
    const float* logits  = (const float*)d_in[0];   // [64,900,91] f32
    const float* boxes   = (const float*)d_in[1];   // [64,900,4]  f32
    const int*   tlabels = (const int*)d_in[2];     // [64,128]    i32 (from i64)
    const float* tboxes  = (const float*)d_in[3];   // [64,128,4]  f32
    int*   out   = (int*)d_out;                     // rows[64,128] ++ cols[64,128]
    float* costT = (float*)d_ws;                    // [64,128,900] f32 = 28.1 MB

    dim3 g1((NN + TPB_C - 1) / TPB_C, BB);          // 8 x 64
    cost_kernel<<<g1, TPB_C, 0, stream>>>(logits, boxes, tlabels, tboxes, costT);
    lsa_kernel<<<BB, 64, 0, stream>>>(costT, out);
}

// Round 5
// 499.667 us; speedup vs baseline: 1.2465x; 1.1030x over previous
//
#include <hip/hip_runtime.h>
#include <hip/hip_bf16.h>
#include <float.h>

#define BB 64
#define NN 900
#define CC 91
#define MM 128
#define BIG 1e18
#define NSLOT 15              // 15*64 = 960 >= 900 columns per lane-slot grid
#define LAST_VALID 4          // slot 14 valid for lanes 0..3 (896+lane < 900)
#define TPB_C 128

// ---------------------------------------------------------------------------
// Kernel 1: cost matrix, stored TRANSPOSED as costT[b][t (M)][p (N)] f32.
// Unchanged from round-3 passing version.
// ---------------------------------------------------------------------------
__global__ __launch_bounds__(TPB_C) void cost_kernel(
    const float* __restrict__ logits,   // [B,N,C]
    const float* __restrict__ boxes,    // [B,N,4]
    const int*   __restrict__ tlabels,  // [B,M]
    const float* __restrict__ tboxes,   // [B,M,4]
    float* __restrict__ costT)          // [B,M,N]
{
    const int b   = blockIdx.y;
    const int p0  = blockIdx.x * TPB_C;
    const int cnt = min(TPB_C, NN - p0);
    const int tid = threadIdx.x;

    __shared__ float s_lg[TPB_C * CC];   // 46592 B
    __shared__ float s_tb[MM][4];
    __shared__ int   s_tl[MM];

    {
        s_tl[tid] = tlabels[b * MM + tid];
        const float4 tb4 = ((const float4*)tboxes)[(size_t)b * MM + tid];
        s_tb[tid][0] = tb4.x; s_tb[tid][1] = tb4.y;
        s_tb[tid][2] = tb4.z; s_tb[tid][3] = tb4.w;
    }
    {
        const float* gbase = logits + ((size_t)b * NN + p0) * CC;
        const int total = cnt * CC;
        const int n4 = total >> 2;
        for (int k = tid; k < n4; k += TPB_C)
            ((float4*)s_lg)[k] = ((const float4*)gbase)[k];
        for (int k = (n4 << 2) + tid; k < total; k += TPB_C)
            s_lg[k] = gbase[k];
    }
    __syncthreads();
    if (tid >= cnt) return;

    const float* lg = s_lg + tid * CC;
    float mx = -INFINITY;
    for (int c = 0; c < CC; ++c) mx = fmaxf(mx, lg[c]);
    float ssum = 0.f;
    for (int c = 0; c < CC; ++c) ssum += expf(lg[c] - mx);

    const float4 bx4 = ((const float4*)boxes)[(size_t)b * NN + p0 + tid];
    const float cx = bx4.x, cy = bx4.y, w = bx4.z, h = bx4.w;
    const float px0 = cx - 0.5f * w, py0 = cy - 0.5f * h;
    const float px1 = cx + 0.5f * w, py1 = cy + 0.5f * h;
    const float parea = (px1 - px0) * (py1 - py0);

    float* outp = costT + (size_t)b * MM * NN + p0 + tid;
    for (int j = 0; j < MM; ++j) {
        const float tcx = s_tb[j][0], tcy = s_tb[j][1], tw = s_tb[j][2], th = s_tb[j][3];
        float l1 = ((fabsf(cx - tcx) + fabsf(cy - tcy)) + fabsf(w - tw)) + fabsf(h - th);
        const float tx0 = tcx - 0.5f * tw, ty0 = tcy - 0.5f * th;
        const float tx1 = tcx + 0.5f * tw, ty1 = tcy + 0.5f * th;
        float iw = fminf(px1, tx1) - fmaxf(px0, tx0); iw = fmaxf(iw, 0.f);
        float ih = fminf(py1, ty1) - fmaxf(py0, ty0); ih = fmaxf(ih, 0.f);
        const float inter = iw * ih;
        const float tarea = (tx1 - tx0) * (ty1 - ty0);
        const float uni   = parea + tarea - inter;
        const float iou   = inter / (uni + 1e-6f);
        const float enc   = (fmaxf(px1, tx1) - fminf(px0, tx0)) *
                            (fmaxf(py1, ty1) - fminf(py0, ty0)) + 1e-6f;
        const float giou  = iou - (enc - uni) / enc;
        const float pcls  = expf(lg[s_tl[j]] - mx) / ssum;
        const float cost  = (1.0f * (-pcls) + 5.0f * l1) + 2.0f * (-giou);
        outp[(size_t)j * NN] = cost;
    }
}

// ---------------------------------------------------------------------------
// Kernel 2: JV LSA, one wave per batch. Round-4 changes (unmeasured, resubmit):
//  - loop rotation: p[j1]/u[p[j1]] read + NEXT row load issued before dual
//    updates (load latency hidden under update work)
//  - first row of each Dijkstra prefetched during previous augmentation;
//    u[i]=0 for a fresh row (never touched), so no LDS read needed
//  - argmin reduce on sortable-u64 key (12 DS ops), delta recovered by
//    inverse transform, j1 via ballot + single shfl (exact int-butterfly
//    fallback on ties). f64 compare semantics preserved bit-exactly.
// ---------------------------------------------------------------------------
__global__ __launch_bounds__(64) void lsa_kernel(
    const float* __restrict__ costT,  // [B,M,N]
    int* __restrict__ out)            // rows [B,M] then cols [B,M], int32
{
    const int b    = blockIdx.x;
    const int lane = threadIdx.x;

    __shared__ double s_u[MM + 1];
    __shared__ int    s_p[NN + 1];
    __shared__ int    s_way[NN + 1];
    __shared__ int    s_c4r[MM];

    double v[NSLOT], minv[NSLOT];
    int    preg[NSLOT];
    float  cv[NSLOT];

    for (int j = lane; j <= NN; j += 64) s_p[j] = 0;
    for (int i = lane; i <= MM; i += 64) s_u[i] = 0.0;
    #pragma unroll
    for (int s = 0; s < NSLOT; ++s) { v[s] = 0.0; preg[s] = 0; }
    __syncthreads();

    const float* cb = costT + (size_t)b * MM * NN;

    // prefetch row 0 (Dijkstra i=1)
    #pragma unroll
    for (int s = 0; s < NSLOT; ++s) {
        const bool valid = (s < NSLOT - 1) || (lane < LAST_VALID);
        cv[s] = valid ? cb[s * 64 + lane] : 0.f;
    }

    for (int i = 1; i <= MM; ++i) {
        unsigned used_mask = 0;
        #pragma unroll
        for (int s = 0; s < NSLOT; ++s) minv[s] = BIG;
        if (lane == 0) s_p[0] = i;
        int j0 = 0;
        double ui0 = 0.0;   // u[i] == 0: row i was never p[0] nor matched before

        while (true) {
            // mark j0 used (column 0 is virtual)
            if (j0 > 0) {
                const int jp = j0 - 1;
                if ((jp & 63) == lane) used_mask |= 1u << (jp >> 6);
            }

            // scan + per-lane argmin (ascending j within lane, strict <)
            double bv = BIG; int bj = 0x7fffffff;
            #pragma unroll
            for (int s = 0; s < NSLOT; ++s) {
                const bool valid = (s < NSLOT - 1) || (lane < LAST_VALID);
                if (valid && !((used_mask >> s) & 1u)) {
                    const int j = s * 64 + lane + 1;
                    const double cur = (double)cv[s] - ui0 - v[s];
                    if (cur < minv[s]) { minv[s] = cur; s_way[j] = j0; }
                    if (minv[s] < bv) { bv = minv[s]; bj = j; }
                }
            }

            // sortable-u64 key; +0.0 normalizes -0 so key== iff double==
            const double bvn = bv + 0.0;
            const long long xb = __double_as_longlong(bvn);
            const unsigned long long mykey =
                (xb < 0) ? ~(unsigned long long)xb
                         : ((unsigned long long)xb | 0x8000000000000000ULL);
            unsigned long long kmin = mykey;
            #pragma unroll
            for (int m = 1; m < 64; m <<= 1) {
                const unsigned long long ok = __shfl_xor(kmin, m);
                if (ok < kmin) kmin = ok;
            }
            // delta = inverse transform of kmin
            const unsigned long long inv =
                (kmin & 0x8000000000000000ULL) ? (kmin ^ 0x8000000000000000ULL) : ~kmin;
            const double delta = __longlong_as_double((long long)inv);

            // j1: smallest j among lanes holding kmin
            const unsigned long long tied = __ballot(mykey == kmin);
            int j1;
            if (__builtin_popcountll(tied) == 1) {
                j1 = __shfl(bj, (int)__builtin_ctzll(tied));
            } else {
                int cand = (mykey == kmin) ? bj : 0x7fffffff;
                #pragma unroll
                for (int m = 1; m < 64; m <<= 1) {
                    const int oc = __shfl_xor(cand, m);
                    if (oc < cand) cand = oc;
                }
                j1 = cand;
            }

            // read p[j1]; pre-read u[p[j1]] (unaffected by this iter's updates);
            // issue next-row loads immediately so latency hides under updates
            const int pj1 = s_p[j1];
            double ui_next = 0.0;
            if (pj1 != 0) {
                ui_next = s_u[pj1];
                const float* crow = cb + (size_t)(pj1 - 1) * NN;
                #pragma unroll
                for (int s = 0; s < NSLOT; ++s) {
                    const bool valid = (s < NSLOT - 1) || (lane < LAST_VALID);
                    if (valid) cv[s] = crow[s * 64 + lane];
                }
            }

            // dual updates (u rows of used columns are distinct; i not among them)
            if (lane == 0) s_u[i] += delta;      // u[p[0]] = u[i]
            double uval[NSLOT];
            #pragma unroll
            for (int s = 0; s < NSLOT; ++s) {
                const bool valid = (s < NSLOT - 1) || (lane < LAST_VALID);
                if (valid && ((used_mask >> s) & 1u)) uval[s] = s_u[preg[s]];
            }
            #pragma unroll
            for (int s = 0; s < NSLOT; ++s) {
                const bool valid = (s < NSLOT - 1) || (lane < LAST_VALID);
                if (valid) {
                    if ((used_mask >> s) & 1u) {
                        s_u[preg[s]] = uval[s] + delta;
                        v[s] -= delta;
                    } else {
                        minv[s] -= delta;
                    }
                }
            }

            if (pj1 == 0) {
                if (lane == 0) {                 // augment along 'way' chain
                    int ja = j1;
                    while (ja) {
                        const int jb = s_way[ja];
                        s_p[ja] = s_p[jb];
                        ja = jb;
                    }
                }
                break;
            }
            j0 = j1; ui0 = ui_next;
        }

        // refresh cached p[j] for this lane's columns
        #pragma unroll
        for (int s = 0; s < NSLOT; ++s) {
            const bool valid = (s < NSLOT - 1) || (lane < LAST_VALID);
            if (valid) preg[s] = s_p[s * 64 + lane + 1];
        }
        // prefetch first row of next Dijkstra (cost row index = i, 0-based)
        if (i < MM) {
            const float* crow = cb + (size_t)i * NN;
            #pragma unroll
            for (int s = 0; s < NSLOT; ++s) {
                const bool valid = (s < NSLOT - 1) || (lane < LAST_VALID);
                if (valid) cv[s] = crow[s * 64 + lane];
            }
        }
    }

    // col4row: target t -> matched pred index
    for (int j = 1 + lane; j <= NN; j += 64) {
        const int pj = s_p[j];
        if (pj > 0) s_c4r[pj - 1] = j - 1;
    }
    __syncthreads();

    // transposed return: rows = sorted pred indices, cols = target permutation
    for (int t = lane; t < MM; t += 64) {
        const int val = s_c4r[t];
        int rank = 0;
        for (int q = 0; q < MM; ++q) rank += (s_c4r[q] < val);
        out[(size_t)b * MM + rank] = val;
        out[(size_t)BB * MM + (size_t)b * MM + rank] = t;
    }
}

extern "C" void kernel_launch(void* const* d_in, const int* in_sizes, int n_in,
                              void* d_out, int out_size, void* d_ws, size_t ws_size,
                              hipStream_t stream) {
    const float* logits  = (const float*)d_in[0];   // [64,900,91] f32
    const float* boxes   = (const float*)d_in[1];   // [64,900,4]  f32
    const int*   tlabels = (const int*)d_in[2];     // [64,128]    i32 (from i64)
    const float* tboxes  = (const float*)d_in[3];   // [64,128,4]  f32
    int*   out   = (int*)d_out;                     // rows[64,128] ++ cols[64,128]
    float* costT = (float*)d_ws;                    // [64,128,900] f32 = 28.1 MB

    dim3 g1((NN + TPB_C - 1) / TPB_C, BB);          // 8 x 64
    cost_kernel<<<g1, TPB_C, 0, stream>>>(logits, boxes, tlabels, tboxes, costT);
    lsa_kernel<<<BB, 64, 0, stream>>>(costT, out);
}